// Round 1
// baseline (88.336 us; speedup 1.0000x reference)
//
#include <hip/hip_runtime.h>

// TensorProduct: out[b, seg[n], c] += CG[n] * x1[b, M1[n], c] * x2[b, M2[n], c]
// B=128, NUM_M=25, C=128, nnz ~ 6.5k, all fp32.
// One wave (64 threads) per (m_out, b-pair): lanes = 2 batches x 32 float4 chunks.
// Segment bounds via 64-lane cooperative lower_bound (3 dependent loads).

#define NUM_M 25
#define B_SZ  128
#define C_DIM 128
#define C4    (C_DIM / 4)   // 32 float4 chunks

__device__ __forceinline__ int wave_lower_bound(const int* __restrict__ seg,
                                                int nnz, int key) {
    const int lane = threadIdx.x & 63;
    int lo = 0, hi = nnz;            // invariant: seg[lo-1] < key <= seg[hi] (sentinels)
    while (hi > lo) {
        const int len = hi - lo;
        const int S = (len + 63) >> 6;          // ceil(len/64)
        const int idx = lo + lane * S;
        bool pred = false;
        if (idx < hi) pred = (seg[idx] < key);
        const unsigned long long bal = __ballot(pred);
        const int c = __popcll(bal);            // first sample >= key is sample #c
        if (c == 0) { hi = lo; break; }         // seg[lo] >= key -> answer = lo
        int nhi = lo + c * S;
        if (nhi > hi) nhi = hi;
        lo = lo + (c - 1) * S + 1;
        hi = nhi;
    }
    return lo;
}

__global__ __launch_bounds__(64) void tp_kernel(
    const float* __restrict__ x1, const float* __restrict__ x2,
    const float* __restrict__ cg, const int* __restrict__ M1,
    const int* __restrict__ M2, const int* __restrict__ seg,
    int nnz, float* __restrict__ out) {

    const int m    = blockIdx.x;          // 0..24  (output M index)
    const int bp   = blockIdx.y;          // 0..63  (batch pair)
    const int lane = threadIdx.x;         // 0..63
    const int b    = bp * 2 + (lane >> 5);
    const int c4   = lane & 31;

    // Cooperative segment bounds (both searches independent -> latencies overlap)
    const int lo = wave_lower_bound(seg, nnz, m);
    const int hi = wave_lower_bound(seg, nnz, m + 1);

    const float4* __restrict__ x1t = ((const float4*)x1) + b * (NUM_M * C4) + c4;
    const float4* __restrict__ x2t = ((const float4*)x2) + b * (NUM_M * C4) + c4;

    float4 acc = make_float4(0.f, 0.f, 0.f, 0.f);

#pragma unroll 4
    for (int n = lo; n < hi; ++n) {
        const int   m1 = M1[n];           // wave-uniform -> scalar loads
        const int   m2 = M2[n];
        const float w  = cg[n];
        const float4 a  = x1t[m1 * C4];   // coalesced 16B/lane, L1/L2-hot
        const float4 bb = x2t[m2 * C4];
        acc.x = fmaf(w * a.x, bb.x, acc.x);
        acc.y = fmaf(w * a.y, bb.y, acc.y);
        acc.z = fmaf(w * a.z, bb.z, acc.z);
        acc.w = fmaf(w * a.w, bb.w, acc.w);
    }

    ((float4*)out)[b * (NUM_M * C4) + m * C4 + c4] = acc;
}

extern "C" void kernel_launch(void* const* d_in, const int* in_sizes, int n_in,
                              void* d_out, int out_size, void* d_ws, size_t ws_size,
                              hipStream_t stream) {
    const float* x1  = (const float*)d_in[0];
    const float* x2  = (const float*)d_in[1];
    const float* cg  = (const float*)d_in[2];
    const int*   M1  = (const int*)d_in[3];
    const int*   M2  = (const int*)d_in[4];
    const int*   seg = (const int*)d_in[5];
    const int    nnz = in_sizes[2];
    float* out = (float*)d_out;

    dim3 grid(NUM_M, B_SZ / 2);   // 25 x 64 = 1600 one-wave blocks
    tp_kernel<<<grid, 64, 0, stream>>>(x1, x2, cg, M1, M2, seg, nnz, out);
}